// Round 1
// baseline (609.847 us; speedup 1.0000x reference)
//
#include <hip/hip_runtime.h>
#include <hip/hip_bf16.h>
#include <cstdint>
#include <cstddef>

// Problem: out[8192,4096] = x[8192,4096] @ W^T + bias + 2.0*((x@A^T)@B^T)
// Fold: W' = W + 2.0 * B@A  (rank-16 update), then out = x @ W'^T + bias.
// Compute in bf16 MFMA (fp32 accumulate) — absmax threshold 0.1156 permits it.

#define IN_F   4096
#define OUT_F  4096
#define MROWS  8192   // 4*2048
#define RLORA  16
#define LORA_SCALE 2.0f

#define BM 128
#define BN 128
#define BK 32

typedef __bf16 bf16x8 __attribute__((ext_vector_type(8)));
typedef float  f32x4  __attribute__((ext_vector_type(4)));

// ---- helpers ---------------------------------------------------------------

__device__ __forceinline__ unsigned short f2bf_rne(float f) {
    union { float f; unsigned u; } v; v.f = f;
    unsigned u = v.u;
    return (unsigned short)((u + 0x7FFFu + ((u >> 16) & 1u)) >> 16);
}

// async global->LDS, 16B per lane; lds dest must be wave-uniform base
__device__ __forceinline__ void gl_lds16(const unsigned short* g, unsigned short* l) {
    __builtin_amdgcn_global_load_lds(
        (const __attribute__((address_space(1))) unsigned int*)g,
        (__attribute__((address_space(3))) unsigned int*)l,
        16, 0, 0);
}

// ---- kernel 1: cast x (fp32 -> bf16), 4 elems/thread -----------------------

__global__ void cast_x_kernel(const float* __restrict__ x,
                              unsigned short* __restrict__ xb) {
    int i = blockIdx.x * blockDim.x + threadIdx.x;   // one per float4
    float4 v = ((const float4*)x)[i];
    ushort4 o;
    o.x = f2bf_rne(v.x); o.y = f2bf_rne(v.y);
    o.z = f2bf_rne(v.z); o.w = f2bf_rne(v.w);
    ((ushort4*)xb)[i] = o;
}

// ---- kernel 2: fold W' = bf16(W + 2*B@A), one block per output row ---------

__global__ void fold_w_kernel(const float* __restrict__ W,
                              const float* __restrict__ A,
                              const float* __restrict__ B,
                              unsigned short* __restrict__ Wp) {
    int o = blockIdx.x;
    __shared__ float sB[RLORA];
    if (threadIdx.x < RLORA) sB[threadIdx.x] = B[o * RLORA + threadIdx.x];
    __syncthreads();
    const float4* W4  = (const float4*)(W + (size_t)o * IN_F);
    ushort4*      Wp4 = (ushort4*)(Wp + (size_t)o * IN_F);
    for (int i4 = threadIdx.x; i4 < IN_F / 4; i4 += blockDim.x) {
        float4 w = W4[i4];
        float ax = 0.f, ay = 0.f, az = 0.f, aw = 0.f;
        #pragma unroll
        for (int r = 0; r < RLORA; ++r) {
            float4 a = ((const float4*)(A + (size_t)r * IN_F))[i4];
            float s = sB[r];
            ax += s * a.x; ay += s * a.y; az += s * a.z; aw += s * a.w;
        }
        w.x += LORA_SCALE * ax; w.y += LORA_SCALE * ay;
        w.z += LORA_SCALE * az; w.w += LORA_SCALE * aw;
        ushort4 ov;
        ov.x = f2bf_rne(w.x); ov.y = f2bf_rne(w.y);
        ov.z = f2bf_rne(w.z); ov.w = f2bf_rne(w.w);
        Wp4[i4] = ov;
    }
}

// ---- kernel 3: C[M,N] = Xb @ Wb^T + bias  (m97-structure bf16 MFMA GEMM) ---
// 128x128 block tile, BK=32, 256 threads = 4 waves in 2x2, each wave 64x64
// via 4x4 grid of 16x16x32 MFMAs. global_load_lds(16B) staging, 2-barrier
// K-loop (explicit dbuf measured neutral on this structure — m99/m100).

__global__ __launch_bounds__(256)
void gemm_bt_bias(const unsigned short* __restrict__ Xb,   // [MROWS][IN_F] bf16
                  const unsigned short* __restrict__ Wb,   // [OUT_F][IN_F] bf16
                  const float* __restrict__ bias,
                  float* __restrict__ out) {               // [MROWS][OUT_F] f32
    __shared__ __align__(16) unsigned short As[BM * BK];   // 8 KB, row-major K=32
    __shared__ __align__(16) unsigned short Bs[BN * BK];   // 8 KB

    const int tid  = threadIdx.x;
    const int wave = tid >> 6;
    const int lane = tid & 63;
    const int quad = lane >> 4;
    const int r16  = lane & 15;
    const int wm   = wave >> 1;   // 2x2 wave grid
    const int wn   = wave & 1;

    const int m0 = blockIdx.y * BM;
    const int n0 = blockIdx.x * BN;

    // Staging: 512 16B-chunks per tile (128 rows x 4 chunks of 8 bf16).
    // Wave w covers chunks [w*128, w*128+128) via two instructions (64 lanes
    // x 16B each). LDS layout == linear chunk order == row-major [row][32].
    const int c0   = wave * 128 + lane;
    const int c1   = c0 + 64;
    const int row0 = c0 >> 2, kc0 = c0 & 3;
    const int row1 = c1 >> 2, kc1 = c1 & 3;

    const unsigned short* gA0 = Xb + (size_t)(m0 + row0) * IN_F + kc0 * 8;
    const unsigned short* gA1 = Xb + (size_t)(m0 + row1) * IN_F + kc1 * 8;
    const unsigned short* gB0 = Wb + (size_t)(n0 + row0) * IN_F + kc0 * 8;
    const unsigned short* gB1 = Wb + (size_t)(n0 + row1) * IN_F + kc1 * 8;

    unsigned short* lA0 = As + (wave * 128 +  0) * 8;   // wave-uniform bases
    unsigned short* lA1 = As + (wave * 128 + 64) * 8;
    unsigned short* lB0 = Bs + (wave * 128 +  0) * 8;
    unsigned short* lB1 = Bs + (wave * 128 + 64) * 8;

    // Fragment read base: A[m = r16 (+16*mi)][k = quad*8 + j]
    const unsigned short* pA = As + ((wm * 64 + r16) * BK) + quad * 8;
    const unsigned short* pB = Bs + ((wn * 64 + r16) * BK) + quad * 8;

    f32x4 acc[4][4] = {};

    for (int k0 = 0; k0 < IN_F; k0 += BK) {
        gl_lds16(gA0, lA0);
        gl_lds16(gA1, lA1);
        gl_lds16(gB0, lB0);
        gl_lds16(gB1, lB1);
        gA0 += BK; gA1 += BK; gB0 += BK; gB1 += BK;
        __syncthreads();   // drains vmcnt: staged data visible

        bf16x8 aF[4], bF[4];
        #pragma unroll
        for (int mi = 0; mi < 4; ++mi)
            aF[mi] = *(const bf16x8*)(pA + mi * 16 * BK);
        #pragma unroll
        for (int ni = 0; ni < 4; ++ni)
            bF[ni] = *(const bf16x8*)(pB + ni * 16 * BK);

        #pragma unroll
        for (int mi = 0; mi < 4; ++mi)
            #pragma unroll
            for (int ni = 0; ni < 4; ++ni)
                acc[mi][ni] = __builtin_amdgcn_mfma_f32_16x16x32_bf16(
                    aF[mi], bF[ni], acc[mi][ni], 0, 0, 0);

        __syncthreads();   // all waves done reading before restage
    }

    // Epilogue: C/D layout col=lane&15, row=quad*4+reg (m89-verified).
    float bv[4];
    #pragma unroll
    for (int ni = 0; ni < 4; ++ni)
        bv[ni] = bias[n0 + wn * 64 + ni * 16 + r16];

    #pragma unroll
    for (int mi = 0; mi < 4; ++mi) {
        #pragma unroll
        for (int i = 0; i < 4; ++i) {
            int mg = m0 + wm * 64 + mi * 16 + quad * 4 + i;
            float* orow = out + (size_t)mg * OUT_F + (n0 + wn * 64 + r16);
            #pragma unroll
            for (int ni = 0; ni < 4; ++ni)
                orow[ni * 16] = acc[mi][ni][i] + bv[ni];
        }
    }
}

// ---- launch ----------------------------------------------------------------

extern "C" void kernel_launch(void* const* d_in, const int* in_sizes, int n_in,
                              void* d_out, int out_size, void* d_ws, size_t ws_size,
                              hipStream_t stream) {
    const float* x    = (const float*)d_in[0];
    const float* W    = (const float*)d_in[1];
    const float* bias = (const float*)d_in[2];
    const float* A    = (const float*)d_in[3];
    const float* B    = (const float*)d_in[4];
    float* out = (float*)d_out;

    unsigned short* xb = (unsigned short*)d_ws;              // 64 MB bf16 x
    unsigned short* wb = xb + (size_t)MROWS * IN_F;          // 32 MB bf16 W'

    cast_x_kernel<<<(MROWS * IN_F) / (4 * 256), 256, 0, stream>>>(x, xb);
    fold_w_kernel<<<OUT_F, 256, 0, stream>>>(W, A, B, wb);

    dim3 grid(OUT_F / BN, MROWS / BM);   // 32 x 64 = 2048 blocks
    gemm_bt_bias<<<grid, 256, 0, stream>>>(xb, wb, bias, out);
}

// Round 2
// 603.950 us; speedup vs baseline: 1.0098x; 1.0098x over previous
//
#include <hip/hip_runtime.h>
#include <hip/hip_bf16.h>
#include <cstdint>
#include <cstddef>

// out[8192,4096] = x @ W^T + bias + 2*((x@A^T)@B^T)
// Fold: W' = W + 2*B@A (rank-16), then ONE bf16 MFMA GEMM: out = x @ W'^T + bias.
// R2: merged prep kernel (cast||fold co-scheduled), XCD-aware GEMM swizzle
//     (W tiles pinned per-XCD L2: 4 tiles x 1 MB = 4 MB = L2 size).

#define IN_F   4096
#define OUT_F  4096
#define MROWS  8192   // 4*2048
#define RLORA  16
#define LORA_SCALE 2.0f

#define BM 128
#define BN 128
#define BK 32

#define CAST_BLOCKS 32768   // MROWS*IN_F / (4*256)
#define FOLD_BLOCKS 4096    // OUT_F

typedef __bf16 bf16x8 __attribute__((ext_vector_type(8)));
typedef float  f32x4  __attribute__((ext_vector_type(4)));

__device__ __forceinline__ unsigned short f2bf_rne(float f) {
    union { float f; unsigned u; } v; v.f = f;
    unsigned u = v.u;
    return (unsigned short)((u + 0x7FFFu + ((u >> 16) & 1u)) >> 16);
}

__device__ __forceinline__ void gl_lds16(const unsigned short* g, unsigned short* l) {
    __builtin_amdgcn_global_load_lds(
        (const __attribute__((address_space(1))) unsigned int*)g,
        (__attribute__((address_space(3))) unsigned int*)l,
        16, 0, 0);
}

// ---- prep: blocks [0,32768) cast x fp32->bf16; [32768,36864) fold W' -------

__global__ void prep_kernel(const float* __restrict__ x,
                            const float* __restrict__ W,
                            const float* __restrict__ A,
                            const float* __restrict__ B,
                            unsigned short* __restrict__ xb,
                            unsigned short* __restrict__ wb) {
    __shared__ float sB[RLORA];
    const int bid = blockIdx.x;
    if (bid < CAST_BLOCKS) {
        int i = bid * blockDim.x + threadIdx.x;       // one float4 per thread
        float4 v = ((const float4*)x)[i];
        ushort4 o;
        o.x = f2bf_rne(v.x); o.y = f2bf_rne(v.y);
        o.z = f2bf_rne(v.z); o.w = f2bf_rne(v.w);
        ((ushort4*)xb)[i] = o;
    } else {
        const int o = bid - CAST_BLOCKS;              // output row
        if (threadIdx.x < RLORA) sB[threadIdx.x] = B[o * RLORA + threadIdx.x];
        __syncthreads();
        const float4* W4  = (const float4*)(W + (size_t)o * IN_F);
        ushort4*      Wp4 = (ushort4*)(wb + (size_t)o * IN_F);
        for (int i4 = threadIdx.x; i4 < IN_F / 4; i4 += blockDim.x) {
            float4 w = W4[i4];
            float ax = 0.f, ay = 0.f, az = 0.f, aw = 0.f;
            #pragma unroll
            for (int r = 0; r < RLORA; ++r) {
                float4 a = ((const float4*)(A + (size_t)r * IN_F))[i4];
                float s = sB[r];
                ax += s * a.x; ay += s * a.y; az += s * a.z; aw += s * a.w;
            }
            w.x += LORA_SCALE * ax; w.y += LORA_SCALE * ay;
            w.z += LORA_SCALE * az; w.w += LORA_SCALE * aw;
            ushort4 ov;
            ov.x = f2bf_rne(w.x); ov.y = f2bf_rne(w.y);
            ov.z = f2bf_rne(w.z); ov.w = f2bf_rne(w.w);
            Wp4[i4] = ov;
        }
    }
}

// ---- GEMM: C[M,N] = Xb @ Wb^T + bias (m97 structure + XCD swizzle) ---------

__global__ __launch_bounds__(256)
void gemm_bt_bias(const unsigned short* __restrict__ Xb,
                  const unsigned short* __restrict__ Wb,
                  const float* __restrict__ bias,
                  float* __restrict__ out) {
    __shared__ __align__(16) unsigned short As[BM * BK];   // 8 KB
    __shared__ __align__(16) unsigned short Bs[BN * BK];   // 8 KB

    const int tid  = threadIdx.x;
    const int wave = tid >> 6;
    const int lane = tid & 63;
    const int quad = lane >> 4;
    const int r16  = lane & 15;
    const int wm   = wave >> 1;
    const int wn   = wave & 1;

    // XCD swizzle: round-robin dispatch puts bid%8 on XCD (bid%8).
    // XCD c owns N-tiles [4c,4c+4): 4 x 1 MB W tiles = its whole 4 MB L2,
    // resident for the entire kernel. Consecutive same-XCD blocks walk M
    // (share each X row-tile 4x in a tight window).
    const int bid = blockIdx.x;
    const int xcd = bid & 7;
    const int t   = bid >> 3;                 // 0..255
    const int n0  = ((xcd << 2) | (t & 3)) * BN;
    const int m0  = (t >> 2) * BM;

    const int c0   = wave * 128 + lane;
    const int c1   = c0 + 64;
    const int row0 = c0 >> 2, kc0 = c0 & 3;
    const int row1 = c1 >> 2, kc1 = c1 & 3;

    const unsigned short* gA0 = Xb + (size_t)(m0 + row0) * IN_F + kc0 * 8;
    const unsigned short* gA1 = Xb + (size_t)(m0 + row1) * IN_F + kc1 * 8;
    const unsigned short* gB0 = Wb + (size_t)(n0 + row0) * IN_F + kc0 * 8;
    const unsigned short* gB1 = Wb + (size_t)(n0 + row1) * IN_F + kc1 * 8;

    unsigned short* lA0 = As + (wave * 128 +  0) * 8;
    unsigned short* lA1 = As + (wave * 128 + 64) * 8;
    unsigned short* lB0 = Bs + (wave * 128 +  0) * 8;
    unsigned short* lB1 = Bs + (wave * 128 + 64) * 8;

    const unsigned short* pA = As + ((wm * 64 + r16) * BK) + quad * 8;
    const unsigned short* pB = Bs + ((wn * 64 + r16) * BK) + quad * 8;

    f32x4 acc[4][4] = {};

    for (int k0 = 0; k0 < IN_F; k0 += BK) {
        gl_lds16(gA0, lA0);
        gl_lds16(gA1, lA1);
        gl_lds16(gB0, lB0);
        gl_lds16(gB1, lB1);
        gA0 += BK; gA1 += BK; gB0 += BK; gB1 += BK;
        __syncthreads();

        bf16x8 aF[4], bF[4];
        #pragma unroll
        for (int mi = 0; mi < 4; ++mi)
            aF[mi] = *(const bf16x8*)(pA + mi * 16 * BK);
        #pragma unroll
        for (int ni = 0; ni < 4; ++ni)
            bF[ni] = *(const bf16x8*)(pB + ni * 16 * BK);

        #pragma unroll
        for (int mi = 0; mi < 4; ++mi)
            #pragma unroll
            for (int ni = 0; ni < 4; ++ni)
                acc[mi][ni] = __builtin_amdgcn_mfma_f32_16x16x32_bf16(
                    aF[mi], bF[ni], acc[mi][ni], 0, 0, 0);

        __syncthreads();
    }

    float bv[4];
    #pragma unroll
    for (int ni = 0; ni < 4; ++ni)
        bv[ni] = bias[n0 + wn * 64 + ni * 16 + r16];

    #pragma unroll
    for (int mi = 0; mi < 4; ++mi) {
        #pragma unroll
        for (int i = 0; i < 4; ++i) {
            int mg = m0 + wm * 64 + mi * 16 + quad * 4 + i;
            float* orow = out + (size_t)mg * OUT_F + (n0 + wn * 64 + r16);
            #pragma unroll
            for (int ni = 0; ni < 4; ++ni)
                orow[ni * 16] = acc[mi][ni][i] + bv[ni];
        }
    }
}

// ---- launch ----------------------------------------------------------------

extern "C" void kernel_launch(void* const* d_in, const int* in_sizes, int n_in,
                              void* d_out, int out_size, void* d_ws, size_t ws_size,
                              hipStream_t stream) {
    const float* x    = (const float*)d_in[0];
    const float* W    = (const float*)d_in[1];
    const float* bias = (const float*)d_in[2];
    const float* A    = (const float*)d_in[3];
    const float* B    = (const float*)d_in[4];
    float* out = (float*)d_out;

    unsigned short* xb = (unsigned short*)d_ws;              // 64 MB bf16 x
    unsigned short* wb = xb + (size_t)MROWS * IN_F;          // 32 MB bf16 W'

    prep_kernel<<<CAST_BLOCKS + FOLD_BLOCKS, 256, 0, stream>>>(x, W, A, B, xb, wb);
    gemm_bt_bias<<<2048, 256, 0, stream>>>(xb, wb, bias, out);
}